// Round 6
// baseline (545.069 us; speedup 1.0000x reference)
//
#include <hip/hip_runtime.h>
#include <math.h>

// DiscriminativeLoss — fused single-read kernel, manual grid barrier.
// Round-6 fix: r4/r5 lost 200+us to SCRATCH DEMOTION of the per-thread pixel
// cache (VGPR=112/128 + WRITE_SIZE=24.7MB while budget was 256): the big
// per-group loops didn't fully unroll, so pk[g]/ids[g] were runtime-indexed
// -> local memory (rule #20). Fix: groups are NAMED variables (pk0/pk1,
// id0/id1) via macros; all loops <=8 iters with tiny bodies; 8 px/thread so
// peak pressure ~120 < the 128 hard cap of launch_bounds(256,4).
//
// embeddings (8,16,512,512) f32, instance_masks (8,512,512) i32 in [0,33)
// out: 4 f32 [total, var, dist, reg]
//
// 1024 blocks x 256 thr. Residency GUARANTEED: launch_bounds(256,4) hard-caps
// VGPR<=128 -> 4 blocks/CU; LDS 29.2KB*4=117KB/CU <=160 -> all 1024 resident.
//   Phase A: 8 px/thread streamed ONCE (16B/lane, channel batches of 8);
//            exact f32 sums via per-wave LDS ds_add histogram; pixels kept as
//            trunc-bf16 pairs in NAMED register arrays. Flush -> gsum atomics.
//   barrier (manual, device-scope, bounded-spin failsafe)
//   Phase B: swizzled LDS means; weighted hinge from register pixels.
//   barrier
//   Phase C: block 0 finalizes (register-accumulated pair loss).
//
// ws: gsum @0 (B*32*17 f32), vsum @20480 (B f32), bar0 @24576, bar1 @24832.

#define B 8
#define E 16
#define HW (512*512)
#define HW4 (HW/4)
#define BLK 256
#define GRID 1024
#define BPI (GRID / B)          // 128 blocks per image
                                // 8 px/thread: 2 int4 groups

#define VSUM_OFF 20480
#define BAR0_OFF 24576
#define BAR1_OFF 24832
#define WS_ZERO  25088

__device__ __forceinline__ float atomAddF(float* p, float v) {
  return unsafeAtomicAdd(p, v);
}
// (trunc-bf16(b)<<16) | trunc-bf16(a) in ONE v_perm_b32  (lo=a, hi=b; verified)
__device__ __forceinline__ unsigned pack_bf(float a, float b) {
  return __builtin_amdgcn_perm(__float_as_uint(b), __float_as_uint(a), 0x07060302u);
}
__device__ __forceinline__ float blo(unsigned u) { return __uint_as_float(u << 16); }
__device__ __forceinline__ float bhi(unsigned u) { return __uint_as_float(u & 0xFFFF0000u); }
__device__ __forceinline__ float gldA(const float* p) {
  return __hip_atomic_load(p, __ATOMIC_RELAXED, __HIP_MEMORY_SCOPE_AGENT);
}

__device__ __forceinline__ void grid_barrier(unsigned* ctr, int t) {
  __syncthreads();
  if (t == 0) {
    __threadfence();
    __hip_atomic_fetch_add(ctr, 1u, __ATOMIC_ACQ_REL, __HIP_MEMORY_SCOPE_AGENT);
    unsigned spins = 0;
    while (__hip_atomic_load(ctr, __ATOMIC_ACQUIRE, __HIP_MEMORY_SCOPE_AGENT)
           < (unsigned)GRID) {
      __builtin_amdgcn_s_sleep(4);
      if (++spins > (1u << 20)) break;   // fail-wrong, never hang
    }
  }
  __syncthreads();
}

// load 8 channel-planes (cb..cb+7) for the 4 px at float4-index vv,
// pack into pkv[px][cb/2 .. cb/2+3], ds_add exact f32 sums.
// All indices compile-time after tiny-loop unroll -> SROA keeps pkv in VGPRs.
#define BATCH8(vv, cb, pkv, idv) do {                                   \
    float4 x_[8];                                                       \
    _Pragma("unroll")                                                   \
    for (int e = 0; e < 8; ++e) x_[e] = embv[(size_t)((cb) + e) * HW4 + (vv)]; \
    _Pragma("unroll")                                                   \
    for (int c = 0; c < 4; ++c) {                                       \
      pkv[0][(cb) / 2 + c] = pack_bf(x_[2 * c].x, x_[2 * c + 1].x);     \
      pkv[1][(cb) / 2 + c] = pack_bf(x_[2 * c].y, x_[2 * c + 1].y);     \
      pkv[2][(cb) / 2 + c] = pack_bf(x_[2 * c].z, x_[2 * c + 1].z);     \
      pkv[3][(cb) / 2 + c] = pack_bf(x_[2 * c].w, x_[2 * c + 1].w);     \
    }                                                                   \
    _Pragma("unroll")                                                   \
    for (int e = 0; e < 8; ++e) {                                       \
      atomicAdd(&hist[wv][idv.x][(cb) + e], x_[e].x);                   \
      atomicAdd(&hist[wv][idv.y][(cb) + e], x_[e].y);                   \
      atomicAdd(&hist[wv][idv.z][(cb) + e], x_[e].z);                   \
      atomicAdd(&hist[wv][idv.w][(cb) + e], x_[e].w);                   \
    }                                                                   \
  } while (0)

// weighted hinge for ONE pixel from its named bf16-pair row (prow[0..7])
#define HPX(prow, idv) do {                                             \
    const int id_ = (idv);                                              \
    const int s_  = id_ + (id_ >> 2);                                   \
    float d_ = 0.f;                                                     \
    _Pragma("unroll")                                                   \
    for (int j = 0; j < 4; ++j) {                                       \
      const float4 m_ = *(const float4*)&mean4[id_][(j + s_) & 3][0];   \
      const unsigned u0_ = (prow)[2 * j], u1_ = (prow)[2 * j + 1];      \
      float u_;                                                         \
      u_ = blo(u0_) - m_.x; d_ += u_ * u_;                              \
      u_ = bhi(u0_) - m_.y; d_ += u_ * u_;                              \
      u_ = blo(u1_) - m_.z; d_ += u_ * u_;                              \
      u_ = bhi(u1_) - m_.w; d_ += u_ * u_;                              \
    }                                                                   \
    const float hh_ = fmaxf(sqrtf(d_) - 0.5f, 0.f);                     \
    vacc += hh_ * hh_ * winv[id_];                                      \
  } while (0)

__global__ __launch_bounds__(BLK, 4) void fused_kernel(
    const float* __restrict__ emb, const int* __restrict__ mask,
    float* __restrict__ gsum /*[B][32][17]*/, float* __restrict__ vsum /*[B]*/,
    unsigned* __restrict__ bar0, unsigned* __restrict__ bar1,
    float* __restrict__ out) {
  __shared__ float hist[4][33][17];                 // 9.0 KB
  __shared__ __align__(16) float mean4[33][4][4];
  __shared__ float winv[33];
  __shared__ float wred[4];
  __shared__ __align__(16) float c_mean[B][32][E];  // 16 KB (block 0 only)
  __shared__ float c_cnt[B][32];
  __shared__ float c_rb[B], c_db[B], c_pb[B], c_nb[B];

  const int t  = threadIdx.x;
  const int wv = t >> 6;
  const int b     = blockIdx.x / BPI;
  const int chunk = blockIdx.x % BPI;
  const int vb    = chunk * (BLK * 2);    // 2 int4-groups per thread

  for (int i = t; i < 4 * 33 * 17; i += BLK) ((float*)hist)[i] = 0.f;
  __syncthreads();

  const int4*   __restrict__ maskv = (const int4*)(mask + (size_t)b * HW);
  const float4* __restrict__ embv  = (const float4*)(emb + (size_t)b * E * HW);

  // NAMED per-group state — no group-indexed arrays anywhere (rule #20)
  unsigned pk0[4][8], pk1[4][8];          // 64 VGPRs of bf16-pair pixel data
  const int v0 = vb + t;
  const int v1 = vb + BLK + t;
  const int4 id0 = maskv[v0];
  const int4 id1 = maskv[v1];

  // ---------------- Phase A ----------------
  BATCH8(v0, 0, pk0, id0);
  BATCH8(v0, 8, pk0, id0);
  atomicAdd(&hist[wv][id0.x][16], 1.f);
  atomicAdd(&hist[wv][id0.y][16], 1.f);
  atomicAdd(&hist[wv][id0.z][16], 1.f);
  atomicAdd(&hist[wv][id0.w][16], 1.f);
  BATCH8(v1, 0, pk1, id1);
  BATCH8(v1, 8, pk1, id1);
  atomicAdd(&hist[wv][id1.x][16], 1.f);
  atomicAdd(&hist[wv][id1.y][16], 1.f);
  atomicAdd(&hist[wv][id1.z][16], 1.f);
  atomicAdd(&hist[wv][id1.w][16], 1.f);
  __syncthreads();

  // flush per-block partials (id 0 = background, discarded)
  for (int i = t; i < 32 * 17; i += BLK) {
    const int id = i / 17 + 1;
    const int e  = i % 17;
    const float s = hist[0][id][e] + hist[1][id][e]
                  + hist[2][id][e] + hist[3][id][e];
    atomAddF(&gsum[((size_t)b * 32 + (id - 1)) * 17 + e], s);
  }

  grid_barrier(bar0, t);

  // ---------------- Phase B ----------------
  for (int i = t; i < 33 * 16; i += BLK) {
    const int k = i >> 4, e = i & 15;
    float m = 0.f;
    if (k >= 1) {
      const float cnt = gldA(&gsum[((size_t)b * 32 + (k - 1)) * 17 + 16]);
      const float cc  = cnt > 1.f ? cnt : 1.f;
      m = gldA(&gsum[((size_t)b * 32 + (k - 1)) * 17 + e]) / cc;
    }
    const int j = e >> 2;
    mean4[k][(j + k + (k >> 2)) & 3][e & 3] = m;   // swizzled (verified)
  }
  if (t < 33) {
    float w = 0.f;
    if (t >= 1) {
      const float cnt = gldA(&gsum[((size_t)b * 32 + (t - 1)) * 17 + 16]);
      w = cnt > 0.5f ? 1.f / cnt : 0.f;
    }
    winv[t] = w;
  }
  __syncthreads();

  float vacc = 0.f;
  HPX(pk0[0], id0.x);
  HPX(pk0[1], id0.y);
  HPX(pk0[2], id0.z);
  HPX(pk0[3], id0.w);
  HPX(pk1[0], id1.x);
  HPX(pk1[1], id1.y);
  HPX(pk1[2], id1.z);
  HPX(pk1[3], id1.w);

#pragma unroll
  for (int off = 32; off >= 1; off >>= 1) vacc += __shfl_down(vacc, off, 64);
  if ((t & 63) == 0) wred[wv] = vacc;
  __syncthreads();
  if (t == 0) atomAddF(&vsum[b], wred[0] + wred[1] + wred[2] + wred[3]);

  grid_barrier(bar1, t);

  // ---------------- Phase C: block 0 ----------------
  if (blockIdx.x != 0) return;
  {
    const int bb = t >> 5, k = t & 31;   // 256 threads = B*32
    const float c  = gldA(&gsum[((size_t)bb * 32 + k) * 17 + 16]);
    const float cc = c > 1.f ? c : 1.f;
    c_cnt[bb][k] = c;
#pragma unroll
    for (int e = 0; e < E; ++e)
      c_mean[bb][k][e] = gldA(&gsum[((size_t)bb * 32 + k) * 17 + e]) / cc;
  }
  if (t < B) { c_rb[t] = 0.f; c_db[t] = 0.f; c_pb[t] = 0.f; c_nb[t] = 0.f; }
  __syncthreads();

  {
    const int bb = t >> 5, k = t & 31;
    const float c = c_cnt[bb][k];
    if (c > 0.5f) {
      atomicAdd(&c_nb[bb], 1.f);
      float sq = 0.f;
#pragma unroll
      for (int e = 0; e < E; ++e) { const float m = c_mean[bb][k][e]; sq += m * m; }
      atomicAdd(&c_rb[bb], sq > 0.f ? sqrtf(sq) : 0.f);
    }
  }

  for (int bb = 0; bb < B; ++bb) {
    float dacc = 0.f, pacc = 0.f;
    for (int p = t; p < 32 * 32; p += BLK) {
      const int i = p >> 5, j = p & 31;
      if (i < j && c_cnt[bb][i] > 0.5f && c_cnt[bb][j] > 0.5f) {
        pacc += 1.f;
        const float4* mi = (const float4*)&c_mean[bb][i][0];
        const float4* mj = (const float4*)&c_mean[bb][j][0];
        float sq = 0.f;
#pragma unroll
        for (int q = 0; q < 4; ++q) {
          const float4 a = mi[q], c4 = mj[q];
          float u;
          u = a.x - c4.x; sq += u * u;  u = a.y - c4.y; sq += u * u;
          u = a.z - c4.z; sq += u * u;  u = a.w - c4.w; sq += u * u;
        }
        const float dn = sq > 0.f ? sqrtf(sq) : 0.f;
        const float hh = 3.0f - dn;    // 2*DELTA_D - d
        if (hh > 0.f) dacc += hh * hh;
      }
    }
#pragma unroll
    for (int off = 32; off >= 1; off >>= 1) {
      dacc += __shfl_down(dacc, off, 64);
      pacc += __shfl_down(pacc, off, 64);
    }
    if ((t & 63) == 0) {
      atomicAdd(&c_db[bb], dacc);
      atomicAdd(&c_pb[bb], pacc);
    }
  }
  __syncthreads();

  if (t == 0) {
    float sv = 0.f, sd = 0.f, sr = 0.f, svalid = 0.f;
    for (int bb = 0; bb < B; ++bb) {
      const float vbv = gldA(&vsum[bb]);
      const float ni  = c_nb[bb];
      const float nim = ni > 1.f ? ni : 1.f;
      const float var_b = vbv / nim;
      const float reg_b = c_rb[bb] / nim;
      const float npm   = c_pb[bb] > 1.f ? c_pb[bb] : 1.f;
      const float dist_b = (ni > 1.f) ? (c_db[bb] / npm) : 0.f;
      const float valid  = ni > 0.f ? 1.f : 0.f;
      sv += var_b * valid;
      sd += dist_b * valid;
      sr += reg_b * valid;
      svalid += valid;
    }
    const float vs = svalid > 1.f ? svalid : 1.f;
    const float var = sv / vs, dist = sd / vs, reg = sr / vs;
    out[0] = var + dist + 0.001f * reg;
    out[1] = var;
    out[2] = dist;
    out[3] = reg;
  }
}

extern "C" void kernel_launch(void* const* d_in, const int* in_sizes, int n_in,
                              void* d_out, int out_size, void* d_ws, size_t ws_size,
                              hipStream_t stream) {
  const float* emb  = (const float*)d_in[0];
  const int*   mask = (const int*)d_in[1];
  float* out = (float*)d_out;

  float*    gsum = (float*)d_ws;
  float*    vsum = (float*)((char*)d_ws + VSUM_OFF);
  unsigned* bar0 = (unsigned*)((char*)d_ws + BAR0_OFF);
  unsigned* bar1 = (unsigned*)((char*)d_ws + BAR1_OFF);

  hipMemsetAsync(d_ws, 0, WS_ZERO, stream);

  fused_kernel<<<dim3(GRID), dim3(BLK), 0, stream>>>(
      emb, mask, gsum, vsum, bar0, bar1, out);
}

// Round 7
// 434.433 us; speedup vs baseline: 1.2547x; 1.2547x over previous
//
#include <hip/hip_runtime.h>
#include <math.h>

// DiscriminativeLoss — two streaming kernels, NO launch-bounds clamp.
// Lesson r2..r6: every kernel with a min-waves launch_bounds got its staging
// registers demoted/serialized by the compiler (VGPR 52/112/128/64, scratch
// WRITE_SIZE up to 36MB, 188-430us). Every uncapped kernel ran <78us.
// Single-read register/LDS pixel caches are dead: regs -> demoted (3 idioms),
// LDS -> 2M px * 32B = 256KB/CU > 160KB. Inputs (136MB) < L3 (256MB), so the
// second read is L3-warm and cheap -- stream twice.
//
// K1: 2048 blocks, 4 px/thread, 17 loads ALL in flight (64 VGPR staging),
//     per-wave LDS histogram (wave-op cost ~2us/CU), flush -> gsum atomics.
// K2: same geometry, f32 hinge vs swizzled LDS means (exact precision),
//     block reduce -> vsum, last-block ticket finalizes (proven r3).
//
// ws: gsum @0 (B*32*17 f32: cols 0..15 sums, col 16 count, segs 1..32),
//     vsum @20480 (B f32), ticket @24576. memset 0..25088.

#define B 8
#define E 16
#define HW (512*512)
#define HW4 (HW/4)
#define BLK 256
#define XBLK 256                 // 2048 blocks total; 1 int4-group/thread
#define NBLOCKS (XBLK * B)

#define VSUM_OFF   20480
#define TICKET_OFF 24576
#define WS_ZERO    25088

__device__ __forceinline__ float atomAddF(float* p, float v) {
  return unsafeAtomicAdd(p, v);
}
__device__ __forceinline__ float gldA(const float* p) {
  return __hip_atomic_load(p, __ATOMIC_RELAXED, __HIP_MEMORY_SCOPE_AGENT);
}

// ---------------- K1: segment sums+counts, per-wave LDS histogram ----------------
__global__ __launch_bounds__(BLK) void hist_kernel(
    const float* __restrict__ emb, const int* __restrict__ mask,
    float* __restrict__ gsum /*[B][32][17]*/) {
  __shared__ float hist[4][33][17];   // 9.0 KB; stride 17 odd -> ids spread banks
  const int b  = blockIdx.y;
  const int t  = threadIdx.x;
  const int wv = t >> 6;

  for (int i = t; i < 4 * 33 * 17; i += BLK) ((float*)hist)[i] = 0.f;
  __syncthreads();

  const int v = blockIdx.x * BLK + t;                  // int4-group index
  const int4 id = ((const int4*)(mask + (size_t)b * HW))[v];
  const float4* __restrict__ embv = (const float4*)(emb + (size_t)b * E * HW);

  float4 x[E];                      // 64 VGPRs — all 16 plane loads in flight
#pragma unroll
  for (int e = 0; e < E; ++e) x[e] = embv[(size_t)e * HW4 + v];

#pragma unroll
  for (int e = 0; e < E; ++e) {
    atomicAdd(&hist[wv][id.x][e], x[e].x);
    atomicAdd(&hist[wv][id.y][e], x[e].y);
    atomicAdd(&hist[wv][id.z][e], x[e].z);
    atomicAdd(&hist[wv][id.w][e], x[e].w);
  }
  atomicAdd(&hist[wv][id.x][16], 1.f);
  atomicAdd(&hist[wv][id.y][16], 1.f);
  atomicAdd(&hist[wv][id.z][16], 1.f);
  atomicAdd(&hist[wv][id.w][16], 1.f);
  __syncthreads();

  // flush per-block partials (id 0 = background, discarded): 544 atomics/block
  for (int i = t; i < 32 * 17; i += BLK) {
    const int id_ = i / 17 + 1;
    const int e   = i % 17;
    const float s = hist[0][id_][e] + hist[1][id_][e]
                  + hist[2][id_][e] + hist[3][id_][e];
    atomAddF(&gsum[((size_t)b * 32 + (id_ - 1)) * 17 + e], s);
  }
}

// ---------------- K2: f32 weighted hinge + last-block finalize ----------------
__global__ __launch_bounds__(BLK) void hinge_kernel(
    const float* __restrict__ emb, const int* __restrict__ mask,
    const float* __restrict__ gsum, float* __restrict__ vsum,
    unsigned* __restrict__ ticket, float* __restrict__ out) {
  // Swizzle: logical chunk j of row k at physical slot (j+k+(k>>2))&3 (verified)
  __shared__ __align__(16) float mean4[33][4][4];
  __shared__ float winv[33];
  __shared__ float wred[4];
  __shared__ unsigned tkt;
  // last-block finalize scratch
  __shared__ __align__(16) float c_mean[B][32][E];  // 16 KB
  __shared__ float c_cnt[B][32];
  __shared__ float c_rb[B], c_db[B], c_pb[B], c_nb[B];

  const int b  = blockIdx.y;
  const int t  = threadIdx.x;
  const int wv = t >> 6;

  // means -> LDS (gsum complete: kernel boundary)
  for (int i = t; i < 33 * 16; i += BLK) {
    const int k = i >> 4, e = i & 15;
    float m = 0.f;
    if (k >= 1) {
      const float cnt = gsum[((size_t)b * 32 + (k - 1)) * 17 + 16];
      const float cc  = cnt > 1.f ? cnt : 1.f;
      m = gsum[((size_t)b * 32 + (k - 1)) * 17 + e] / cc;
    }
    const int j = e >> 2;
    mean4[k][(j + k + (k >> 2)) & 3][e & 3] = m;
  }
  if (t < 33) {
    float w = 0.f;
    if (t >= 1) {
      const float cnt = gsum[((size_t)b * 32 + (t - 1)) * 17 + 16];
      w = cnt > 0.5f ? 1.f / cnt : 0.f;
    }
    winv[t] = w;
  }
  __syncthreads();

  const int v = blockIdx.x * BLK + t;
  const int4 id = ((const int4*)(mask + (size_t)b * HW))[v];
  const float4* __restrict__ embv = (const float4*)(emb + (size_t)b * E * HW);

  float4 x[E];                      // all 16 plane loads in flight
#pragma unroll
  for (int e = 0; e < E; ++e) x[e] = embv[(size_t)e * HW4 + v];

  const int sx = id.x + (id.x >> 2);
  const int sy = id.y + (id.y >> 2);
  const int sz = id.z + (id.z >> 2);
  const int sw = id.w + (id.w >> 2);

  float d0 = 0.f, d1 = 0.f, d2 = 0.f, d3 = 0.f;
#pragma unroll
  for (int j = 0; j < 4; ++j) {
    const float4 m0 = *(const float4*)&mean4[id.x][(j + sx) & 3][0];
    const float4 m1 = *(const float4*)&mean4[id.y][(j + sy) & 3][0];
    const float4 m2 = *(const float4*)&mean4[id.z][(j + sz) & 3][0];
    const float4 m3 = *(const float4*)&mean4[id.w][(j + sw) & 3][0];
    const float4 a0 = x[4 * j + 0], a1 = x[4 * j + 1];
    const float4 a2 = x[4 * j + 2], a3 = x[4 * j + 3];
    float u;
    u = a0.x - m0.x; d0 += u * u;  u = a1.x - m0.y; d0 += u * u;
    u = a2.x - m0.z; d0 += u * u;  u = a3.x - m0.w; d0 += u * u;
    u = a0.y - m1.x; d1 += u * u;  u = a1.y - m1.y; d1 += u * u;
    u = a2.y - m1.z; d1 += u * u;  u = a3.y - m1.w; d1 += u * u;
    u = a0.z - m2.x; d2 += u * u;  u = a1.z - m2.y; d2 += u * u;
    u = a2.z - m2.z; d2 += u * u;  u = a3.z - m2.w; d2 += u * u;
    u = a0.w - m3.x; d3 += u * u;  u = a1.w - m3.y; d3 += u * u;
    u = a2.w - m3.z; d3 += u * u;  u = a3.w - m3.w; d3 += u * u;
  }
  float vacc = 0.f, hh;             // winv[0]=0 kills background
  hh = fmaxf(sqrtf(d0) - 0.5f, 0.f); vacc += hh * hh * winv[id.x];
  hh = fmaxf(sqrtf(d1) - 0.5f, 0.f); vacc += hh * hh * winv[id.y];
  hh = fmaxf(sqrtf(d2) - 0.5f, 0.f); vacc += hh * hh * winv[id.z];
  hh = fmaxf(sqrtf(d3) - 0.5f, 0.f); vacc += hh * hh * winv[id.w];

  // block reduce -> one global atomic
#pragma unroll
  for (int off = 32; off >= 1; off >>= 1) vacc += __shfl_down(vacc, off, 64);
  if ((t & 63) == 0) wred[wv] = vacc;
  __syncthreads();

  if (t == 0) {
    atomAddF(&vsum[b], wred[0] + wred[1] + wred[2] + wred[3]);
    __threadfence();                      // vsum add ordered before ticket
    tkt = atomicAdd(ticket, 1u);
  }
  __syncthreads();
  if (tkt != NBLOCKS - 1) return;

  // ---------------- last block: finalize (proven r3) ----------------
  __threadfence();
  {
    const int bb = t >> 5, k = t & 31;    // 256 threads = B*32 exactly
    const float c  = gldA(&gsum[((size_t)bb * 32 + k) * 17 + 16]);
    const float cc = c > 1.f ? c : 1.f;
    c_cnt[bb][k] = c;
#pragma unroll
    for (int e = 0; e < E; ++e)
      c_mean[bb][k][e] = gldA(&gsum[((size_t)bb * 32 + k) * 17 + e]) / cc;
  }
  if (t < B) { c_rb[t] = 0.f; c_db[t] = 0.f; c_pb[t] = 0.f; c_nb[t] = 0.f; }
  __syncthreads();

  {
    const int bb = t >> 5, k = t & 31;
    const float c = c_cnt[bb][k];
    if (c > 0.5f) {
      atomicAdd(&c_nb[bb], 1.f);
      float sq = 0.f;
#pragma unroll
      for (int e = 0; e < E; ++e) { const float m = c_mean[bb][k][e]; sq += m * m; }
      atomicAdd(&c_rb[bb], sq > 0.f ? sqrtf(sq) : 0.f);
    }
  }

  for (int bb = 0; bb < B; ++bb) {
    float dacc = 0.f, pacc = 0.f;
    for (int p = t; p < 32 * 32; p += BLK) {
      const int i = p >> 5, j = p & 31;
      if (i < j && c_cnt[bb][i] > 0.5f && c_cnt[bb][j] > 0.5f) {
        pacc += 1.f;
        const float4* mi = (const float4*)&c_mean[bb][i][0];
        const float4* mj = (const float4*)&c_mean[bb][j][0];
        float sq = 0.f;
#pragma unroll
        for (int q = 0; q < 4; ++q) {
          const float4 a = mi[q], c4 = mj[q];
          float u;
          u = a.x - c4.x; sq += u * u;  u = a.y - c4.y; sq += u * u;
          u = a.z - c4.z; sq += u * u;  u = a.w - c4.w; sq += u * u;
        }
        const float dn = sq > 0.f ? sqrtf(sq) : 0.f;
        const float hh2 = 3.0f - dn;     // 2*DELTA_D - d
        if (hh2 > 0.f) dacc += hh2 * hh2;
      }
    }
#pragma unroll
    for (int off = 32; off >= 1; off >>= 1) {
      dacc += __shfl_down(dacc, off, 64);
      pacc += __shfl_down(pacc, off, 64);
    }
    if ((t & 63) == 0) {
      atomicAdd(&c_db[bb], dacc);
      atomicAdd(&c_pb[bb], pacc);
    }
  }
  __syncthreads();

  if (t == 0) {
    float sv = 0.f, sd = 0.f, sr = 0.f, svalid = 0.f;
    for (int bb = 0; bb < B; ++bb) {
      const float vbv = gldA(&vsum[bb]);
      const float ni  = c_nb[bb];
      const float nim = ni > 1.f ? ni : 1.f;
      const float var_b = vbv / nim;
      const float reg_b = c_rb[bb] / nim;
      const float npm   = c_pb[bb] > 1.f ? c_pb[bb] : 1.f;
      const float dist_b = (ni > 1.f) ? (c_db[bb] / npm) : 0.f;
      const float valid  = ni > 0.f ? 1.f : 0.f;
      sv += var_b * valid;
      sd += dist_b * valid;
      sr += reg_b * valid;
      svalid += valid;
    }
    const float vs = svalid > 1.f ? svalid : 1.f;
    const float var = sv / vs, dist = sd / vs, reg = sr / vs;
    out[0] = var + dist + 0.001f * reg;
    out[1] = var;
    out[2] = dist;
    out[3] = reg;
  }
}

extern "C" void kernel_launch(void* const* d_in, const int* in_sizes, int n_in,
                              void* d_out, int out_size, void* d_ws, size_t ws_size,
                              hipStream_t stream) {
  const float* emb  = (const float*)d_in[0];
  const int*   mask = (const int*)d_in[1];
  float* out = (float*)d_out;

  float*    gsum   = (float*)d_ws;
  float*    vsum   = (float*)((char*)d_ws + VSUM_OFF);
  unsigned* ticket = (unsigned*)((char*)d_ws + TICKET_OFF);

  hipMemsetAsync(d_ws, 0, WS_ZERO, stream);

  hist_kernel <<<dim3(XBLK, B), BLK, 0, stream>>>(emb, mask, gsum);
  hinge_kernel<<<dim3(XBLK, B), BLK, 0, stream>>>(emb, mask, gsum, vsum, ticket, out);
}

// Round 8
// 348.869 us; speedup vs baseline: 1.5624x; 1.2453x over previous
//
#include <hip/hip_runtime.h>
#include <math.h>

// DiscriminativeLoss — r0-proven MFMA pass1 (+bf16 copy byproduct) + bf16 pass2.
// embeddings (8,16,512,512) f32, instance_masks (8,512,512) i32 in [0,33)
// out: 4 f32 [total, var, dist, reg]
//
// Evidence: r2/r7 proved hipcc serializes wide load batches whose consumers
// are LDS atomics (190us, VGPR 36-52) — the LDS-histogram pass1 is dead.
// r0's MFMA one-hot pass1 is the only proven-fast segment-sum (<78us).
// pass2's cost is its 136MB f32 re-stream -> halve it: pass1 emits a 64MB
// px-pair-major bf16 copy (it already packs bf16 for MFMA), pass2 reads that.
// bf16-trunc hinge precision proven r5/r6 (absmax 0.0625 <= 0.4175).
//
// ws: gsum @0 (B*32*17 f32), vsum @20480, ticket @24576, emb16 @32768 (64MB).
// Copy layout: uint idx = (b*HW+px)/2*16 + c  ->  bf16(ch c, px even) |
//              bf16(ch c, px odd)<<16  (px-pair-major, 16 uints per pair).

#define B 8
#define E 16
#define HW (512*512)
#define HW4 (HW/4)
#define BLK 256
#define P1_BPI 128              // 1024 blocks; 4 waves/block, 512 px/wave
#define P2_XBLK 512             // 4096 blocks; 1 px-pair/thread
#define NBLOCKS (P2_XBLK * B)

#define VSUM_OFF   20480
#define TICKET_OFF 24576
#define EMB16_OFF  32768
#define WS_ZERO    25088

typedef __attribute__((ext_vector_type(8)))  short short8;
typedef __attribute__((ext_vector_type(16))) float floatx16;

__device__ __forceinline__ float atomAddF(float* p, float v) {
  return unsafeAtomicAdd(p, v);
}
// trunc-bf16(a) | trunc-bf16(b)<<16 in ONE v_perm_b32 (harness-verified r0/r5)
__device__ __forceinline__ unsigned pack_bf(float a, float b) {
  return __builtin_amdgcn_perm(__float_as_uint(b), __float_as_uint(a), 0x07060302u);
}
__device__ __forceinline__ float blo(unsigned u) { return __uint_as_float(u << 16); }
__device__ __forceinline__ float bhi(unsigned u) { return __uint_as_float(u & 0xFFFF0000u); }
__device__ __forceinline__ float gldA(const float* p) {
  return __hip_atomic_load(p, __ATOMIC_RELAXED, __HIP_MEMORY_SCOPE_AGENT);
}

// ---------------- Pass 1: r0 MFMA one-hot + bf16 copy byproduct ----------------
__global__ __launch_bounds__(BLK) void pass1_kernel(
    const float* __restrict__ emb, const int* __restrict__ mask,
    float* __restrict__ gsum /*[B][32][17]*/, unsigned* __restrict__ emb16) {
  __shared__ int4 mstage[4][128];                    // per-wave mask stage (8 KB)
  __shared__ __align__(16) float lred[4][32][33];    // cross-wave reduce
  __shared__ unsigned tpose[4][128];                 // per-wave copy transpose (2 KB)
  const int b    = blockIdx.y;
  const int t    = threadIdx.x;
  const int lane = t & 63;
  const int wv   = __builtin_amdgcn_readfirstlane(t >> 6);
  const int n    = lane & 31;        // A: row m (segment id-1). B/D: col n (channel).
  const int h    = lane >> 5;        // k-half: k = 8*h + j
  const int myid = n + 1;
  const bool ld  = (n < 16);

  const int ppw    = HW / (P1_BPI * 4);          // 512 pixels per wave
  const int ntiles = ppw / 16;                   // 32
  const int base   = (blockIdx.x * 4 + wv) * ppw;

  // ---- stage this wave's 512 mask values into LDS (2 coalesced int4 loads) ----
  {
    const int4* __restrict__ mg = (const int4*)(mask + (size_t)b * HW + base);
    mstage[wv][lane]      = mg[lane];
    mstage[wv][64 + lane] = mg[64 + lane];
  }
  __syncthreads();

  const float* __restrict__ pl = emb + ((size_t)b * E + (n & 15)) * HW + base + 8 * h;

  floatx16 acc;
#pragma unroll
  for (int i = 0; i < 16; ++i) acc[i] = 0.f;

  // ---- 4-deep ring: tiles tl..tl+3 always in flight ----
  float4 fb[4][2];
#pragma unroll
  for (int u = 0; u < 4; ++u) {
    if (ld) {
      fb[u][0] = ((const float4*)(pl + u * 16))[0];
      fb[u][1] = ((const float4*)(pl + u * 16))[1];
    }
  }

  for (int tl4 = 0; tl4 < ntiles; tl4 += 4) {
#pragma unroll
    for (int u = 0; u < 4; ++u) {
      const int tl = tl4 + u;

      const int4 A0 = mstage[wv][tl * 4 + 2 * h];
      const int4 A1 = mstage[wv][tl * 4 + 2 * h + 1];

      short8 af;
      af[0] = (A0.x == myid) ? (short)0x3F80 : (short)0;
      af[1] = (A0.y == myid) ? (short)0x3F80 : (short)0;
      af[2] = (A0.z == myid) ? (short)0x3F80 : (short)0;
      af[3] = (A0.w == myid) ? (short)0x3F80 : (short)0;
      af[4] = (A1.x == myid) ? (short)0x3F80 : (short)0;
      af[5] = (A1.y == myid) ? (short)0x3F80 : (short)0;
      af[6] = (A1.z == myid) ? (short)0x3F80 : (short)0;
      af[7] = (A1.w == myid) ? (short)0x3F80 : (short)0;

      short8 bf;
      if (ld) {
        union { uint4 u4; short8 s; } cv;
        cv.u4.x = pack_bf(fb[u][0].x, fb[u][0].y);
        cv.u4.y = pack_bf(fb[u][0].z, fb[u][0].w);
        cv.u4.z = pack_bf(fb[u][1].x, fb[u][1].y);
        cv.u4.w = pack_bf(fb[u][1].z, fb[u][1].w);
        bf = cv.s;
        // bf16 copy staging: word cw of cv = (channel n, px-pair 4h+cw)
        tpose[wv][(4 * h + 0) * 16 + n] = cv.u4.x;
        tpose[wv][(4 * h + 1) * 16 + n] = cv.u4.y;
        tpose[wv][(4 * h + 2) * 16 + n] = cv.u4.z;
        tpose[wv][(4 * h + 3) * 16 + n] = cv.u4.w;
      } else if (n == 16) {
        const short one = (short)0x3F80;
        bf[0]=one; bf[1]=one; bf[2]=one; bf[3]=one; bf[4]=one; bf[5]=one; bf[6]=one; bf[7]=one;
      } else {
        bf[0]=0; bf[1]=0; bf[2]=0; bf[3]=0; bf[4]=0; bf[5]=0; bf[6]=0; bf[7]=0;
      }

      acc = __builtin_amdgcn_mfma_f32_32x32x16_bf16(af, bf, acc, 0, 0, 0);

      // refill slot u with tile tl+4
      const int tn = tl + 4;
      if (tn < ntiles && ld) {
        fb[u][0] = ((const float4*)(pl + tn * 16))[0];
        fb[u][1] = ((const float4*)(pl + tn * 16))[1];
      }

      // copy write-back: 128 uints px-pair-major, uint2 per lane, coalesced
      {
        uint2 w;
        w.x = tpose[wv][2 * lane];
        w.y = tpose[wv][2 * lane + 1];
        ((uint2*)emb16)[((size_t)b * HW + base + tl * 16) * 4 + lane] = w;
      }
    }
  }

  // C/D layout (verified): col = lane&31, row = (r&3)+8*(r>>2)+4*(lane>>5)
#pragma unroll
  for (int r = 0; r < 16; ++r) {
    const int row = (r & 3) + 8 * (r >> 2) + 4 * h;
    lred[wv][row][n] = acc[r];
  }
  __syncthreads();

  for (int i = t; i < 32 * 32; i += BLK) {
    const int row = i >> 5, col = i & 31;
    if (col < 17) {
      const float s = lred[0][row][col] + lred[1][row][col]
                    + lred[2][row][col] + lred[3][row][col];
      atomAddF(&gsum[((size_t)b * 32 + row) * 17 + col], s);
    }
  }
}

// ---------------- Pass 2: bf16 hinge + last-block finalize ----------------
__global__ __launch_bounds__(BLK) void pass2_kernel(
    const unsigned* __restrict__ emb16, const int* __restrict__ mask,
    const float* __restrict__ gsum, float* __restrict__ vsum,
    unsigned* __restrict__ ticket, float* __restrict__ out) {
  __shared__ __align__(16) float mean4[33][4][4];   // swizzled (verified)
  __shared__ float winv[33];
  __shared__ float wred[4];
  __shared__ unsigned tkt;
  __shared__ __align__(16) float c_mean[B][32][E];
  __shared__ float c_cnt[B][32];
  __shared__ float c_rb[B], c_db[B], c_pb[B], c_nb[B];

  const int b  = blockIdx.y;
  const int t  = threadIdx.x;
  const int wv = t >> 6;

  for (int i = t; i < 33 * 16; i += BLK) {
    const int k = i >> 4, e = i & 15;
    float m = 0.f;
    if (k >= 1) {
      const float cnt = gsum[((size_t)b * 32 + (k - 1)) * 17 + 16];
      const float cc  = cnt > 1.f ? cnt : 1.f;
      m = gsum[((size_t)b * 32 + (k - 1)) * 17 + e] / cc;
    }
    const int j = e >> 2;
    mean4[k][(j + k + (k >> 2)) & 3][e & 3] = m;
  }
  if (t < 33) {
    float w = 0.f;
    if (t >= 1) {
      const float cnt = gsum[((size_t)b * 32 + (t - 1)) * 17 + 16];
      w = cnt > 0.5f ? 1.f / cnt : 0.f;
    }
    winv[t] = w;
  }
  __syncthreads();

  const int pp = blockIdx.x * BLK + t;             // px-pair index, 0..HW/2-1
  const int2 id2 = ((const int2*)(mask + (size_t)b * HW))[pp];
  const uint4* __restrict__ cp = (const uint4*)emb16 + ((size_t)b * (HW / 2) + pp) * 4;
  const uint4 U0 = cp[0], U1 = cp[1], U2 = cp[2], U3 = cp[3];

  const int ide = id2.x, ido = id2.y;
  const int se = ide + (ide >> 2);
  const int so = ido + (ido >> 2);
  float de = 0.f, dd = 0.f;

#define JBLK(UU, jj) do {                                                 \
    const float4 me = *(const float4*)&mean4[ide][((jj) + se) & 3][0];    \
    const float4 mo = *(const float4*)&mean4[ido][((jj) + so) & 3][0];    \
    float u_;                                                             \
    u_ = blo(UU.x) - me.x; de += u_ * u_;                                 \
    u_ = bhi(UU.x) - mo.x; dd += u_ * u_;                                 \
    u_ = blo(UU.y) - me.y; de += u_ * u_;                                 \
    u_ = bhi(UU.y) - mo.y; dd += u_ * u_;                                 \
    u_ = blo(UU.z) - me.z; de += u_ * u_;                                 \
    u_ = bhi(UU.z) - mo.z; dd += u_ * u_;                                 \
    u_ = blo(UU.w) - me.w; de += u_ * u_;                                 \
    u_ = bhi(UU.w) - mo.w; dd += u_ * u_;                                 \
  } while (0)

  JBLK(U0, 0);
  JBLK(U1, 1);
  JBLK(U2, 2);
  JBLK(U3, 3);
#undef JBLK

  float vacc = 0.f, hh;             // winv[0]=0 kills background
  hh = fmaxf(sqrtf(de) - 0.5f, 0.f); vacc += hh * hh * winv[ide];
  hh = fmaxf(sqrtf(dd) - 0.5f, 0.f); vacc += hh * hh * winv[ido];

#pragma unroll
  for (int off = 32; off >= 1; off >>= 1) vacc += __shfl_down(vacc, off, 64);
  if ((t & 63) == 0) wred[wv] = vacc;
  __syncthreads();

  if (t == 0) {
    atomAddF(&vsum[b], wred[0] + wred[1] + wred[2] + wred[3]);
    __threadfence();
    tkt = atomicAdd(ticket, 1u);
  }
  __syncthreads();
  if (tkt != NBLOCKS - 1) return;

  // ---------------- last block: finalize (proven r3/r7) ----------------
  __threadfence();
  {
    const int bb = t >> 5, k = t & 31;    // 256 threads = B*32 exactly
    const float c  = gldA(&gsum[((size_t)bb * 32 + k) * 17 + 16]);
    const float cc = c > 1.f ? c : 1.f;
    c_cnt[bb][k] = c;
#pragma unroll
    for (int e = 0; e < E; ++e)
      c_mean[bb][k][e] = gldA(&gsum[((size_t)bb * 32 + k) * 17 + e]) / cc;
  }
  if (t < B) { c_rb[t] = 0.f; c_db[t] = 0.f; c_pb[t] = 0.f; c_nb[t] = 0.f; }
  __syncthreads();

  {
    const int bb = t >> 5, k = t & 31;
    const float c = c_cnt[bb][k];
    if (c > 0.5f) {
      atomicAdd(&c_nb[bb], 1.f);
      float sq = 0.f;
#pragma unroll
      for (int e = 0; e < E; ++e) { const float m = c_mean[bb][k][e]; sq += m * m; }
      atomicAdd(&c_rb[bb], sq > 0.f ? sqrtf(sq) : 0.f);
    }
  }

  for (int bb = 0; bb < B; ++bb) {
    float dacc = 0.f, pacc = 0.f;
    for (int p = t; p < 32 * 32; p += BLK) {
      const int i = p >> 5, j = p & 31;
      if (i < j && c_cnt[bb][i] > 0.5f && c_cnt[bb][j] > 0.5f) {
        pacc += 1.f;
        const float4* mi = (const float4*)&c_mean[bb][i][0];
        const float4* mj = (const float4*)&c_mean[bb][j][0];
        float sq = 0.f;
#pragma unroll
        for (int q = 0; q < 4; ++q) {
          const float4 a = mi[q], c4 = mj[q];
          float u;
          u = a.x - c4.x; sq += u * u;  u = a.y - c4.y; sq += u * u;
          u = a.z - c4.z; sq += u * u;  u = a.w - c4.w; sq += u * u;
        }
        const float dn = sq > 0.f ? sqrtf(sq) : 0.f;
        const float hh2 = 3.0f - dn;     // 2*DELTA_D - d
        if (hh2 > 0.f) dacc += hh2 * hh2;
      }
    }
#pragma unroll
    for (int off = 32; off >= 1; off >>= 1) {
      dacc += __shfl_down(dacc, off, 64);
      pacc += __shfl_down(pacc, off, 64);
    }
    if ((t & 63) == 0) {
      atomicAdd(&c_db[bb], dacc);
      atomicAdd(&c_pb[bb], pacc);
    }
  }
  __syncthreads();

  if (t == 0) {
    float sv = 0.f, sd = 0.f, sr = 0.f, svalid = 0.f;
    for (int bb = 0; bb < B; ++bb) {
      const float vbv = gldA(&vsum[bb]);
      const float ni  = c_nb[bb];
      const float nim = ni > 1.f ? ni : 1.f;
      const float var_b = vbv / nim;
      const float reg_b = c_rb[bb] / nim;
      const float npm   = c_pb[bb] > 1.f ? c_pb[bb] : 1.f;
      const float dist_b = (ni > 1.f) ? (c_db[bb] / npm) : 0.f;
      const float valid  = ni > 0.f ? 1.f : 0.f;
      sv += var_b * valid;
      sd += dist_b * valid;
      sr += reg_b * valid;
      svalid += valid;
    }
    const float vs = svalid > 1.f ? svalid : 1.f;
    const float var = sv / vs, dist = sd / vs, reg = sr / vs;
    out[0] = var + dist + 0.001f * reg;
    out[1] = var;
    out[2] = dist;
    out[3] = reg;
  }
}

extern "C" void kernel_launch(void* const* d_in, const int* in_sizes, int n_in,
                              void* d_out, int out_size, void* d_ws, size_t ws_size,
                              hipStream_t stream) {
  const float* emb  = (const float*)d_in[0];
  const int*   mask = (const int*)d_in[1];
  float* out = (float*)d_out;

  float*    gsum  = (float*)d_ws;
  float*    vsum  = (float*)((char*)d_ws + VSUM_OFF);
  unsigned* ticket= (unsigned*)((char*)d_ws + TICKET_OFF);
  unsigned* emb16 = (unsigned*)((char*)d_ws + EMB16_OFF);   // 64 MB

  hipMemsetAsync(d_ws, 0, WS_ZERO, stream);

  pass1_kernel<<<dim3(P1_BPI, B), BLK, 0, stream>>>(emb, mask, gsum, emb16);
  pass2_kernel<<<dim3(P2_XBLK, B), BLK, 0, stream>>>(emb16, mask, gsum, vsum, ticket, out);
}